// Round 1
// baseline (16.013 us; speedup 1.0000x reference)
//
#include <hip/hip_runtime.h>
#include <stdint.h>

#define NUM_GRAPHS 8192
#define NODES_PER_GRAPH 128
#define TOTAL_NODES (NUM_GRAPHS * NODES_PER_GRAPH)
#define C 128

typedef __attribute__((ext_vector_type(8))) short bf16x8;
typedef __attribute__((ext_vector_type(4))) float f32x4;

// f32 -> bf16 bits, round-to-nearest-even (inputs are finite normals; no NaN path needed)
static __device__ __forceinline__ short f2bf(float f) {
    union { float f; uint32_t u; } v; v.f = f;
    const uint32_t u = v.u;
    return (short)((u + 0x7fffu + ((u >> 16) & 1u)) >> 16);
}

// Fully parallel first-occurrence scatter: batch is sorted, every graph id present,
// so first_idx[b] = i  iff  (i == 0 || batch[i-1] != batch[i]).
__global__ void first_occ_kernel(const int* __restrict__ batch, int* __restrict__ fidx) {
    const int i = blockIdx.x * blockDim.x + threadIdx.x;
    if (i >= TOTAL_NODES) return;
    const int b = batch[i];
    if ((i == 0 || batch[i - 1] != b) && (unsigned)b < (unsigned)NUM_GRAPHS)
        fidx[b] = i;
}

// One wave (64 thr) per 16 graphs; computes out[g0:g0+16][0:128] = gather(x) @ W^T + b
// via 8 col-tiles x 4 k-chunks of v_mfma_f32_16x16x32_bf16. No LDS.
__global__ __launch_bounds__(64) void pool_linear_kernel(
        const float* __restrict__ x, const float* __restrict__ W,
        const float* __restrict__ bias, const int* __restrict__ fidx,
        float* __restrict__ out) {
    const int l  = threadIdx.x;
    const int r  = l & 15;   // A-row / B-col / D-col within tile
    const int kg = l >> 4;   // k-group
    const int gbase = blockIdx.x * 16;

    // A fragments: gathered row of x, converted to bf16. Loaded once, reused for all 8 col-tiles.
    const int fi = fidx[gbase + r];
    const float* xrow = x + (size_t)fi * C;
    bf16x8 a[4];
#pragma unroll
    for (int kc = 0; kc < 4; ++kc) {
        const int k0 = kc * 32 + kg * 8;
        const float4 lo = *reinterpret_cast<const float4*>(xrow + k0);
        const float4 hi = *reinterpret_cast<const float4*>(xrow + k0 + 4);
        a[kc][0] = f2bf(lo.x); a[kc][1] = f2bf(lo.y); a[kc][2] = f2bf(lo.z); a[kc][3] = f2bf(lo.w);
        a[kc][4] = f2bf(hi.x); a[kc][5] = f2bf(hi.y); a[kc][6] = f2bf(hi.z); a[kc][7] = f2bf(hi.w);
    }

#pragma unroll
    for (int ct = 0; ct < 8; ++ct) {
        const int col = ct * 16 + r;                 // B col = D col = lane&15
        const float* wrow = W + (size_t)col * C;     // out[g][col] = sum_k pooled[g][k] * W[col][k]
        const float bc = bias[col];
        f32x4 acc = {bc, bc, bc, bc};                // D rows all share this lane's col -> same bias
#pragma unroll
        for (int kc = 0; kc < 4; ++kc) {
            const int k0 = kc * 32 + kg * 8;
            const float4 lo = *reinterpret_cast<const float4*>(wrow + k0);
            const float4 hi = *reinterpret_cast<const float4*>(wrow + k0 + 4);
            bf16x8 bf;
            bf[0] = f2bf(lo.x); bf[1] = f2bf(lo.y); bf[2] = f2bf(lo.z); bf[3] = f2bf(lo.w);
            bf[4] = f2bf(hi.x); bf[5] = f2bf(hi.y); bf[6] = f2bf(hi.z); bf[7] = f2bf(hi.w);
            acc = __builtin_amdgcn_mfma_f32_16x16x32_bf16(a[kc], bf, acc, 0, 0, 0);
        }
        // C/D layout (verified m89): col = lane&15, row = (lane>>4)*4 + reg
#pragma unroll
        for (int reg = 0; reg < 4; ++reg) {
            const int row = gbase + kg * 4 + reg;
            out[(size_t)row * C + col] = acc[reg];
        }
    }
}

extern "C" void kernel_launch(void* const* d_in, const int* in_sizes, int n_in,
                              void* d_out, int out_size, void* d_ws, size_t ws_size,
                              hipStream_t stream) {
    const float* x     = (const float*)d_in[0];
    const int*   batch = (const int*)d_in[1];
    const float* W     = (const float*)d_in[2];
    const float* b     = (const float*)d_in[3];
    float*       out   = (float*)d_out;
    int*         fidx  = (int*)d_ws;   // NUM_GRAPHS ints = 32 KB scratch

    first_occ_kernel<<<TOTAL_NODES / 256, 256, 0, stream>>>(batch, fidx);
    pool_linear_kernel<<<NUM_GRAPHS / 16, 64, 0, stream>>>(x, W, b, fidx, out);
}